// Round 15
// baseline (46.940 us; speedup 1.0000x reference)
//
#include <hip/hip_runtime.h>

// B=8, N=2048, D=32, H=4, HD=8, BH=32
// ws layout (15MB):
//   q16    [32][2048][8]   f16 (1MB) @ 0     c1*log2e pre-folded
//   kf_ws  [32][64][64][8] f16 (2MB) @ 1MB   K frags, jt-PAIR packed
//   vf_ws  [32][64][64][8] f16 (2MB) @ 3MB   V^T frags, jt-pair packed (+ones d=8)
//   adj16  [64][128][64][8] f16 (8MB) @ 5MB  exp2(c2*adj), C-frag order, qt-pair packed
//   attn_ws[8][2048][32]   f32 (2MB) @ 13MB
//
// R15 = R14 (46.2us) + LDS-instruction diet in the two small kernels:
//  - qkv: x-row in registers + float2 W reads -> 128 LDS instrs/thread (was 384)
//  - out_ln: LDS-staged attn rows + transposed Wout -> 16 LDS b128 (was 64
//    scalar global loads + 32 strided LDS reads). attn kernel unchanged.

typedef _Float16 f16;
typedef _Float16 f16x4 __attribute__((ext_vector_type(4)));
typedef _Float16 f16x8 __attribute__((ext_vector_type(8)));
typedef __fp16 h16x2 __attribute__((ext_vector_type(2)));
typedef __fp16 h16x8 __attribute__((ext_vector_type(8)));
typedef float f32x4 __attribute__((ext_vector_type(4)));

// Blocks [0,512): coalesced adj swizzle (64 qtp x 8 col-chunks) + const fill.
// Blocks [512,1536): qkv projection (16 rows each).
__global__ __launch_bounds__(256) void prep_qkv_kernel(
    const float* __restrict__ x, const float* __restrict__ Wqkv,
    const float* __restrict__ bqkv, const float* __restrict__ adj,
    const float* __restrict__ gw_p, f16* __restrict__ q16,
    f16* __restrict__ kf_ws, f16* __restrict__ vf_ws,
    f16* __restrict__ adj16) {
  const float LOG2E = 1.4426950408889634f;
  float blend = 1.f / (1.f + __expf(-gw_p[0]));
  int tid = threadIdx.x;
  __shared__ union {
    float als[32][260];                      // padded: stride 260 -> 2-way max
    struct { float Ws[32 * 96]; float bsh[96]; float xs[16 * 33]; } qk;
  } u;

  if (blockIdx.x < 512) {
    // ---- constant-lane fill for packed kf/vf ----
    int g = blockIdx.x * 256 + tid;          // 131072 = 32bh*64jtp*64lane
    int glane = g & 63;
    const f16x8 z8 = {};
    if (glane >= 32) *(f16x8*)(kf_ws + (size_t)g * 8) = z8;
    int glq = glane & 15;
    if (glq == 8) {
      f16x8 o8 = {(f16)1.f, (f16)1.f, (f16)1.f, (f16)1.f,
                  (f16)1.f, (f16)1.f, (f16)1.f, (f16)1.f};
      *(f16x8*)(vf_ws + (size_t)g * 8) = o8;
    } else if (glq > 8) {
      *(f16x8*)(vf_ws + (size_t)g * 8) = z8;
    }
    // ---- coalesced adj read -> LDS -> swizzled exp2 f16 write ----
    float c2 = blend * 5.f * LOG2E;
    int qtp = blockIdx.x >> 3;               // 0..63
    int chunk = blockIdx.x & 7;              // 256 cols each
    const float* src = adj + (size_t)(qtp * 32) * 2048 + chunk * 256;
#pragma unroll
    for (int i = 0; i < 8; ++i) {
      int idx = i * 1024 + tid * 4;          // 32 rows x 256 cols
      int row = idx >> 8, col = idx & 255;
      f32x4 v = *(const f32x4*)(src + (size_t)row * 2048 + col);
      *(f32x4*)&u.als[row][col] = v;
    }
    __syncthreads();
#pragma unroll
    for (int i = 0; i < 4; ++i) {
      int flat = i * 256 + tid;              // 16 jt x 64 lanes
      int jt_l = flat >> 6, lane = flat & 63;
      int lq = lane & 15, lh = lane >> 4;
      int col0 = jt_l * 16 + lh * 4;
      f16x8 r;
#pragma unroll
      for (int e = 0; e < 8; ++e)
        r[e] = (f16)__builtin_amdgcn_exp2f(
            c2 * u.als[(e < 4 ? 0 : 16) + lq][col0 + (e & 3)]);
      int jt = chunk * 16 + jt_l;
      *(f16x8*)(adj16 + (((size_t)qtp * 128 + jt) * 64 + lane) * 8) = r;
    }
  } else {
    float c1 = (1.f - blend) * 0.35355339059327373f * LOG2E;
    int blk = blockIdx.x - 512;
    for (int i = tid; i < 32 * 96; i += 256) u.qk.Ws[i] = Wqkv[i];
    if (tid < 96) u.qk.bsh[tid] = bqkv[tid];
    int rowbase = blk * 16;
    for (int i = tid; i < 512; i += 256) {   // xs padded [16][33]
      int r = i >> 5, k = i & 31;
      u.qk.xs[r * 33 + k] = x[(size_t)(rowbase + r) * 32 + k];
    }
    __syncthreads();
    // thread = (row r, 6 consecutive cols c0..c0+5); x-row in registers.
    int r = tid >> 4, c0 = (tid & 15) * 6;
    float xr[32];
#pragma unroll
    for (int k = 0; k < 32; ++k) xr[k] = u.qk.xs[r * 33 + k];
    float acc[6];
#pragma unroll
    for (int e = 0; e < 6; ++e) acc[e] = u.qk.bsh[c0 + e];
#pragma unroll
    for (int k = 0; k < 32; ++k) {
      const float* wp = &u.qk.Ws[k * 96 + c0];
      float2 w01 = *(const float2*)wp;
      float2 w23 = *(const float2*)(wp + 2);
      float2 w45 = *(const float2*)(wp + 4);
      acc[0] = fmaf(xr[k], w01.x, acc[0]);
      acc[1] = fmaf(xr[k], w01.y, acc[1]);
      acc[2] = fmaf(xr[k], w23.x, acc[2]);
      acc[3] = fmaf(xr[k], w23.y, acc[3]);
      acc[4] = fmaf(xr[k], w45.x, acc[4]);
      acc[5] = fmaf(xr[k], w45.y, acc[5]);
    }
    int nrow = rowbase + r;
    int b = nrow >> 11, n = nrow & 2047;
    int jt = n >> 4, jr = n & 15;
#pragma unroll
    for (int e = 0; e < 6; ++e) {
      int c = c0 + e;
      int s = c >> 5, h = (c >> 3) & 3, d = c & 7;
      int bh = b * 4 + h;
      if (s == 0) {
        q16[((size_t)bh * 2048 + n) * 8 + d] = (f16)(acc[e] * c1);
      } else if (s == 1) {
        int lane = ((d >> 2) << 4) | jr;
        kf_ws[(((size_t)bh * 64 + (jt >> 1)) * 64 + lane) * 8 +
              (jt & 1) * 4 + (d & 3)] = (f16)acc[e];
      } else {
        int lane = ((jr >> 2) << 4) | d;
        vf_ws[(((size_t)bh * 64 + (jt >> 1)) * 64 + lane) * 8 +
              (jt & 1) * 4 + (jr & 3)] = (f16)acc[e];
      }
    }
  }
}

__global__ __launch_bounds__(512, 4) void attn_kernel(
    const f16* __restrict__ q16, const f16* __restrict__ kf_ws,
    const f16* __restrict__ vf_ws, const f16* __restrict__ adj16,
    float* __restrict__ attn_ws) {
  // XCD swizzle: each chunk owns 4 qtq -> 1MB adj16 slice in L2.
  int blk = blockIdx.x;                 // 512 blocks
  int chunk = blk & 7;
  int within = blk >> 3;                // 0..63
  int bhp = within & 15;                // 16 bh-pairs (adj-sharing, same XCD)
  int qtq = (chunk << 2) | (within >> 4);  // 32 qt-quads
  int tid = threadIdx.x;
  int w = tid >> 6, lane = tid & 63;    // w = j-split (16 jt = 8 jt-pairs)
  int lq = lane & 15, lh = lane >> 4;
  int bh0 = bhp * 2;

  const f16* kp = kf_ws + (((size_t)bh0 * 64 + w * 8) * 64 + lane) * 8;
  const f16* vp = vf_ws + (((size_t)bh0 * 64 + w * 8) * 64 + lane) * 8;
  const f16* ap0 = adj16 + (((size_t)(qtq * 2) * 128 + w * 16) * 64 + lane) * 8;
  const f16* ap1 = ap0 + (size_t)128 * 64 * 8;

  f16x4 qf[2][4];
#pragma unroll
  for (int uu = 0; uu < 2; ++uu)
#pragma unroll
    for (int m = 0; m < 4; ++m) {
      f16x4 t = {};
      if (lane < 32)
        t = *(const f16x4*)(q16 + ((size_t)(bh0 + uu) * 2048 +
                                   (qtq * 4 + m) * 16 + lq) * 8 + lh * 4);
      qf[uu][m] = t;
    }

  f32x4 acc[2][4];
#pragma unroll
  for (int uu = 0; uu < 2; ++uu)
#pragma unroll
    for (int m = 0; m < 4; ++m) acc[uu][m] = (f32x4){0.f, 0.f, 0.f, 0.f};
  const f32x4 zero4 = {0.f, 0.f, 0.f, 0.f};

#pragma unroll 2
  for (int tp = 0; tp < 8; ++tp) {      // 8 jt-pairs = 16 j-tiles
    f16x8 kf80 = *(const f16x8*)(kp + tp * 512);
    f16x8 kf81 = *(const f16x8*)(kp + 32768 + tp * 512);
    f16x8 vf80 = *(const f16x8*)(vp + tp * 512);
    f16x8 vf81 = *(const f16x8*)(vp + 32768 + tp * 512);
    h16x8 a0a = *(const h16x8*)(ap0 + (tp * 2) * 512);
    h16x8 a0b = *(const h16x8*)(ap0 + (tp * 2 + 1) * 512);
    h16x8 a1a = *(const h16x8*)(ap1 + (tp * 2) * 512);
    h16x8 a1b = *(const h16x8*)(ap1 + (tp * 2 + 1) * 512);
#pragma unroll
    for (int jh = 0; jh < 2; ++jh) {
      f16x4 kf0 = {kf80[jh * 4], kf80[jh * 4 + 1], kf80[jh * 4 + 2], kf80[jh * 4 + 3]};
      f16x4 kf1 = {kf81[jh * 4], kf81[jh * 4 + 1], kf81[jh * 4 + 2], kf81[jh * 4 + 3]};
      f16x4 vf0 = {vf80[jh * 4], vf80[jh * 4 + 1], vf80[jh * 4 + 2], vf80[jh * 4 + 3]};
      f16x4 vf1 = {vf81[jh * 4], vf81[jh * 4 + 1], vf81[jh * 4 + 2], vf81[jh * 4 + 3]};
      h16x8 av0 = jh ? a0b : a0a;
      h16x8 av1 = jh ? a1b : a1a;
#pragma unroll
      for (int uu = 0; uu < 2; ++uu) {
        f16x4 kfu = uu ? kf1 : kf0;
        f16x4 vfu = uu ? vf1 : vf0;
#pragma unroll
        for (int m = 0; m < 4; ++m) {
          f32x4 s = __builtin_amdgcn_mfma_f32_16x16x16f16(kfu, qf[uu][m], zero4, 0, 0, 0);
          h16x8 av = (m < 2) ? av0 : av1;
          int b4 = (m & 1) * 4;
          float e0 = __builtin_amdgcn_exp2f(s[0]);
          float e1 = __builtin_amdgcn_exp2f(s[1]);
          float e2 = __builtin_amdgcn_exp2f(s[2]);
          float e3 = __builtin_amdgcn_exp2f(s[3]);
          h16x2 p01 = __builtin_amdgcn_cvt_pkrtz(e0, e1);
          h16x2 p23 = __builtin_amdgcn_cvt_pkrtz(e2, e3);
          h16x2 ea01 = {av[b4 + 0], av[b4 + 1]};
          h16x2 ea23 = {av[b4 + 2], av[b4 + 3]};
          p01 *= ea01;   // v_pk_mul_f16: p = exp2(s) * exp2(c2*adj)
          p23 *= ea23;
          f16x4 pa;
          pa[0] = (f16)(float)p01[0]; pa[1] = (f16)(float)p01[1];
          pa[2] = (f16)(float)p23[0]; pa[3] = (f16)(float)p23[1];
          acc[uu][m] = __builtin_amdgcn_mfma_f32_16x16x16f16(pa, vfu, acc[uu][m], 0, 0, 0);
        }
      }
    }
  }

  // merge 8 j-split partials; parallel epilogue: wave w reduces slot p=w.
  __shared__ f32x4 mlds[8][8][64];  // 64KB
#pragma unroll
  for (int uu = 0; uu < 2; ++uu)
#pragma unroll
    for (int m = 0; m < 4; ++m) mlds[w][uu * 4 + m][lane] = acc[uu][m];
  __syncthreads();
  int p = w;
  f32x4 sum = mlds[0][p][lane];
#pragma unroll
  for (int s = 1; s < 8; ++s) {
    f32x4 o = mlds[s][p][lane];
    sum[0] += o[0]; sum[1] += o[1]; sum[2] += o[2]; sum[3] += o[3];
  }
  int dsrc = (lane & 48) | 8;
  float d0 = __shfl(sum[0], dsrc);
  float d1 = __shfl(sum[1], dsrc);
  float d2 = __shfl(sum[2], dsrc);
  float d3 = __shfl(sum[3], dsrc);
  if (lq < 8) {
    int bh = bh0 + (p >> 2);
    int b = bh >> 2, h = bh & 3;
    int qt0 = (qtq * 4 + (p & 3)) * 16;
    size_t base = ((size_t)b * 2048 + qt0 + lh * 4) * 32 + h * 8 + lq;
    attn_ws[base]      = sum[0] / d0;
    attn_ws[base + 32] = sum[1] / d1;
    attn_ws[base + 64] = sum[2] / d2;
    attn_ws[base + 96] = sum[3] / d3;
  }
}

__global__ __launch_bounds__(256) void out_ln_kernel(
    const float* __restrict__ attn_ws, const float* __restrict__ x,
    const float* __restrict__ Wout, const float* __restrict__ bout,
    const float* __restrict__ gamma, const float* __restrict__ beta,
    float* __restrict__ out) {
  __shared__ float WsT[32][36];   // transposed Wout, padded
  __shared__ float bs[32], gs[32], bts[32];
  __shared__ float arow[8][32];
  int tid = threadIdx.x;
  for (int i = tid; i < 1024; i += 256) WsT[i & 31][i >> 5] = Wout[i];
  if (tid < 32) { bs[tid] = bout[tid]; gs[tid] = gamma[tid]; bts[tid] = beta[tid]; }
  int row0 = blockIdx.x * 8;
  arow[tid >> 5][tid & 31] =
      attn_ws[(size_t)(row0 + (tid >> 5)) * 32 + (tid & 31)];
  __syncthreads();
  int rg = tid >> 5, d = tid & 31;
  int row = row0 + rg;
  float acc = bs[d];
  const float4* a4 = (const float4*)&arow[rg][0];
#pragma unroll
  for (int kk = 0; kk < 8; ++kk) {
    float4 a = a4[kk];
    float4 wv = *(const float4*)&WsT[d][kk * 4];
    acc = fmaf(a.x, wv.x, acc);
    acc = fmaf(a.y, wv.y, acc);
    acc = fmaf(a.z, wv.z, acc);
    acc = fmaf(a.w, wv.w, acc);
  }
  float res = acc + x[(size_t)row * 32 + d];
  float s1 = res, s2 = res * res;
#pragma unroll
  for (int off = 16; off >= 1; off >>= 1) {
    s1 += __shfl_xor(s1, off);
    s2 += __shfl_xor(s2, off);
  }
  float mu = s1 * 0.03125f;
  float var = s2 * 0.03125f - mu * mu;
  float r = rsqrtf(var + 1e-5f);
  out[(size_t)row * 32 + d] = (res - mu) * r * gs[d] + bts[d];
}

extern "C" void kernel_launch(void* const* d_in, const int* in_sizes, int n_in,
                              void* d_out, int out_size, void* d_ws, size_t ws_size,
                              hipStream_t stream) {
  const float* x     = (const float*)d_in[0];
  const float* adj   = (const float*)d_in[1];
  const float* gw    = (const float*)d_in[2];
  const float* Wqkv  = (const float*)d_in[3];
  const float* bqkv  = (const float*)d_in[4];
  const float* Wout  = (const float*)d_in[5];
  const float* bout  = (const float*)d_in[6];
  const float* gamma = (const float*)d_in[7];
  const float* beta  = (const float*)d_in[8];
  float* out = (float*)d_out;

  char* wsb = (char*)d_ws;
  f16* q16       = (f16*)wsb;                     // 1MB
  f16* kf_ws     = (f16*)(wsb + (1 << 20));       // 2MB
  f16* vf_ws     = (f16*)(wsb + (3 << 20));       // 2MB
  f16* adj16     = (f16*)(wsb + (5 << 20));       // 8MB
  float* attn_ws = (float*)(wsb + (13 << 20));    // 2MB

  prep_qkv_kernel<<<1536, 256, 0, stream>>>(x, Wqkv, bqkv, adj, gw,
                                            q16, kf_ws, vf_ws, adj16);
  attn_kernel<<<512, 512, 0, stream>>>(q16, kf_ws, vf_ws, adj16, attn_ws);
  out_ln_kernel<<<2048, 256, 0, stream>>>(attn_ws, x, Wout, bout, gamma, beta, out);
}